// Round 4
// baseline (933.772 us; speedup 1.0000x reference)
//
#include <hip/hip_runtime.h>
#include <hip/hip_fp16.h>

#define NNODES 60000
#define NEDGES 960000
#define NGRAPH 10000

struct __align__(16) H8 { __half2 h[4]; };
struct __align__(8)  H4 { __half2 h[2]; };

typedef _Float16 f16x8 __attribute__((ext_vector_type(8)));
typedef float f32x4 __attribute__((ext_vector_type(4)));

// ---------------- degree / CSR build ----------------

__global__ void count_deg_k(const int* __restrict__ ei, int* __restrict__ deg) {
  int e = blockIdx.x * blockDim.x + threadIdx.x;
  atomicAdd(&deg[ei[NEDGES + e]], 1);
}

__global__ void dinv_k(const int* __restrict__ deg, float* __restrict__ dinv) {
  int i = blockIdx.x * blockDim.x + threadIdx.x;
  if (i < NNODES) dinv[i] = rsqrtf((float)deg[i] + 1.0f);
}

__global__ void scan1_k(const int* __restrict__ deg, int* __restrict__ rs, int* __restrict__ bsum) {
  __shared__ int s[256];
  int tid = threadIdx.x;
  int i = blockIdx.x * 256 + tid;
  int v = (i < NNODES) ? deg[i] : 0;
  int x = v;
  s[tid] = x; __syncthreads();
  #pragma unroll
  for (int off = 1; off < 256; off <<= 1) {
    int t = (tid >= off) ? s[tid - off] : 0;
    __syncthreads();
    x += t; s[tid] = x; __syncthreads();
  }
  if (i < NNODES) rs[i] = x - v;
  if (tid == 255) bsum[blockIdx.x] = x;
}

__global__ void scan2_k(int* __restrict__ bsum, int nb) {
  __shared__ int s[256];
  int tid = threadIdx.x;
  int v = (tid < nb) ? bsum[tid] : 0;
  int x = v; s[tid] = x; __syncthreads();
  #pragma unroll
  for (int off = 1; off < 256; off <<= 1) {
    int t = (tid >= off) ? s[tid - off] : 0;
    __syncthreads();
    x += t; s[tid] = x; __syncthreads();
  }
  if (tid < nb) bsum[tid] = x - v;
}

__global__ void scan3_k(int* __restrict__ rs, const int* __restrict__ bsum) {
  int i = blockIdx.x * 256 + threadIdx.x;
  if (i < NNODES) rs[i] += bsum[blockIdx.x];
  if (i == 0) rs[NNODES] = NEDGES;
}

__global__ void scatter_k(const int* __restrict__ ei, const int* __restrict__ rs,
                          int* __restrict__ cursor, unsigned short* __restrict__ csr) {
  int e = blockIdx.x * blockDim.x + threadIdx.x;
  int s = ei[e], d = ei[NEDGES + e];
  int pos = rs[d] + atomicAdd(&cursor[d], 1);
  csr[pos] = (unsigned short)s;
}

// ---------------- fp32 -> fp16 convert (state) ----------------

__global__ void f2h_k(const float* __restrict__ in, __half* __restrict__ out) {
  int i = blockIdx.x * blockDim.x + threadIdx.x;   // one H8 per thread
  float4 a = *reinterpret_cast<const float4*>(in + (size_t)i * 8);
  float4 b = *reinterpret_cast<const float4*>(in + (size_t)i * 8 + 4);
  H8 o;
  o.h[0].x = __float2half_rn(a.x); o.h[0].y = __float2half_rn(a.y);
  o.h[1].x = __float2half_rn(a.z); o.h[1].y = __float2half_rn(a.w);
  o.h[2].x = __float2half_rn(b.x); o.h[2].y = __float2half_rn(b.y);
  o.h[3].x = __float2half_rn(b.z); o.h[3].y = __float2half_rn(b.w);
  *reinterpret_cast<H8*>(out + (size_t)i * 8) = o;
}

// ---------------- weight transpose+convert: WhT[n][k] = fp16(W[k][n]) ----------------

__global__ void wconv_k(const float* __restrict__ W, __half* __restrict__ WhT) {
  int n = blockIdx.x, k = threadIdx.x;
  WhT[n * 256 + k] = __float2half_rn(W[k * 256 + n]);
}

// ---------------- MFMA GEMM: Y[r] = fp16((X @ W)[r] * dinv[r]) ----------------

#define LDP 56

__launch_bounds__(256)
__global__ void gemm_mfma_k(const __half* __restrict__ Xh, const __half* __restrict__ WhT,
                            const float* __restrict__ dinv, __half* __restrict__ Y) {
  __shared__ _Float16 As[128][LDP];
  __shared__ _Float16 Bs[128][LDP];
  const int tid = threadIdx.x;
  const int n0 = (blockIdx.x & 1) * 128;
  const int m0 = (blockIdx.x >> 1) * 128;
  const int lane = tid & 63;
  const int wid = tid >> 6;
  const int wr = wid >> 1, wc = wid & 1;
  const int li = lane & 15, lg = lane >> 4;

  f32x4 acc[4][4];
  #pragma unroll
  for (int i = 0; i < 4; ++i)
    #pragma unroll
    for (int j = 0; j < 4; ++j) acc[i][j] = (f32x4){0.f, 0.f, 0.f, 0.f};

  for (int k0 = 0; k0 < 256; k0 += 32) {
    #pragma unroll
    for (int l = 0; l < 2; ++l) {
      int f = tid + l * 256;
      int row = f >> 2, cq = (f & 3) * 8;
      int gr = m0 + row; if (gr >= NNODES) gr = NNODES - 1;
      *reinterpret_cast<H8*>(&As[row][cq]) =
          *reinterpret_cast<const H8*>(Xh + (size_t)gr * 256 + k0 + cq);
      *reinterpret_cast<H8*>(&Bs[row][cq]) =
          *reinterpret_cast<const H8*>(WhT + (size_t)(n0 + row) * 256 + k0 + cq);
    }
    __syncthreads();
    f16x8 a[4], b[4];
    #pragma unroll
    for (int rf = 0; rf < 4; ++rf)
      a[rf] = *reinterpret_cast<const f16x8*>(&As[wr * 64 + rf * 16 + li][lg * 8]);
    #pragma unroll
    for (int cf = 0; cf < 4; ++cf)
      b[cf] = *reinterpret_cast<const f16x8*>(&Bs[wc * 64 + cf * 16 + li][lg * 8]);
    #pragma unroll
    for (int rf = 0; rf < 4; ++rf)
      #pragma unroll
      for (int cf = 0; cf < 4; ++cf)
        acc[rf][cf] = __builtin_amdgcn_mfma_f32_16x16x32_f16(b[cf], a[rf], acc[rf][cf], 0, 0, 0);
    __syncthreads();
  }

  #pragma unroll
  for (int rf = 0; rf < 4; ++rf) {
    int r = m0 + wr * 64 + rf * 16 + li;
    if (r < NNODES) {
      float dv = dinv[r];
      #pragma unroll
      for (int cf = 0; cf < 4; ++cf) {
        int n = n0 + wc * 64 + cf * 16 + lg * 4;
        H4 o;
        o.h[0].x = __float2half_rn(acc[rf][cf][0] * dv);
        o.h[0].y = __float2half_rn(acc[rf][cf][1] * dv);
        o.h[1].x = __float2half_rn(acc[rf][cf][2] * dv);
        o.h[1].y = __float2half_rn(acc[rf][cf][3] * dv);
        *reinterpret_cast<H4*>(Y + (size_t)r * 256 + n) = o;
      }
    }
  }
}

// ---------------- gather: o[d] = fp16(relu(dinv[d]*(ys[d] + sum ys[src]) + b)) ----------
// XCD-channel-sliced: block bid%8 handles a 32-channel (64 B) slice; with round-robin
// block->XCD dispatch, each XCD's edge-read working set is 60000x64B = 3.84 MB < 4 MB L2.
// 4 lanes per dst node, 8 fp16 channels per lane.

__device__ inline void addH8(float* acc, const H8& v) {
  #pragma unroll
  for (int q = 0; q < 4; ++q) {
    acc[q * 2 + 0] += __low2float(v.h[q]);
    acc[q * 2 + 1] += __high2float(v.h[q]);
  }
}

__global__ void gather_k(const __half* __restrict__ ysh, const int* __restrict__ rs,
                         const unsigned short* __restrict__ csr, const float* __restrict__ dinv,
                         const float* __restrict__ bias, __half* __restrict__ out) {
  int slice = blockIdx.x & 7;
  int chunk = blockIdx.x >> 3;
  int d = chunk * 64 + (threadIdx.x >> 2);
  if (d >= NNODES) return;
  int c = slice * 32 + (threadIdx.x & 3) * 8;

  float acc[8];
  H8 self = *reinterpret_cast<const H8*>(ysh + (size_t)d * 256 + c);
  #pragma unroll
  for (int q = 0; q < 4; ++q) {
    acc[q * 2 + 0] = __low2float(self.h[q]);
    acc[q * 2 + 1] = __high2float(self.h[q]);
  }

  int e = rs[d], end = rs[d + 1];
  for (; e + 1 < end; e += 2) {
    int s0 = csr[e], s1 = csr[e + 1];
    H8 v0 = *reinterpret_cast<const H8*>(ysh + (size_t)s0 * 256 + c);
    H8 v1 = *reinterpret_cast<const H8*>(ysh + (size_t)s1 * 256 + c);
    addH8(acc, v0);
    addH8(acc, v1);
  }
  if (e < end) {
    int s0 = csr[e];
    H8 v0 = *reinterpret_cast<const H8*>(ysh + (size_t)s0 * 256 + c);
    addH8(acc, v0);
  }

  float dv = dinv[d];
  float4 b0 = *reinterpret_cast<const float4*>(bias + c);
  float4 b1 = *reinterpret_cast<const float4*>(bias + c + 4);
  float r0 = fmaxf(acc[0] * dv + b0.x, 0.f);
  float r1 = fmaxf(acc[1] * dv + b0.y, 0.f);
  float r2 = fmaxf(acc[2] * dv + b0.z, 0.f);
  float r3 = fmaxf(acc[3] * dv + b0.w, 0.f);
  float r4 = fmaxf(acc[4] * dv + b1.x, 0.f);
  float r5 = fmaxf(acc[5] * dv + b1.y, 0.f);
  float r6 = fmaxf(acc[6] * dv + b1.z, 0.f);
  float r7 = fmaxf(acc[7] * dv + b1.w, 0.f);
  H8 o;
  o.h[0].x = __float2half_rn(r0); o.h[0].y = __float2half_rn(r1);
  o.h[1].x = __float2half_rn(r2); o.h[1].y = __float2half_rn(r3);
  o.h[2].x = __float2half_rn(r4); o.h[2].y = __float2half_rn(r5);
  o.h[3].x = __float2half_rn(r6); o.h[3].y = __float2half_rn(r7);
  *reinterpret_cast<H8*>(out + (size_t)d * 256 + c) = o;
}

// ---------------- skern: h1acc[32 rows/block] += in @ lw  (in fp16) ----------------

__launch_bounds__(256)
__global__ void skern_k(const __half* __restrict__ in, const float* __restrict__ lw,
                        float* __restrict__ h1acc) {
  __shared__ float os[32][256];
  int tid = threadIdx.x;
  int n0 = blockIdx.x * 32;
  #pragma unroll
  for (int l = 0; l < 4; ++l) {
    int f = tid + l * 256;
    int row = f >> 5, c8 = (f & 31) * 8;
    H8 v = *reinterpret_cast<const H8*>(in + (size_t)(n0 + row) * 256 + c8);
    float* dst = &os[row][c8];
    dst[0] = __low2float(v.h[0]); dst[1] = __high2float(v.h[0]);
    dst[2] = __low2float(v.h[1]); dst[3] = __high2float(v.h[1]);
    dst[4] = __low2float(v.h[2]); dst[5] = __high2float(v.h[2]);
    dst[6] = __low2float(v.h[3]); dst[7] = __high2float(v.h[3]);
  }
  __syncthreads();
  int dim = tid & 31, rblk = tid >> 5;
  float a0 = 0.f, a1 = 0.f, a2 = 0.f, a3 = 0.f;
  #pragma unroll 8
  for (int k = 0; k < 256; ++k) {
    float w = lw[k * 32 + dim];
    a0 += os[rblk * 4 + 0][k] * w;
    a1 += os[rblk * 4 + 1][k] * w;
    a2 += os[rblk * 4 + 2][k] * w;
    a3 += os[rblk * 4 + 3][k] * w;
  }
  int base = (n0 + rblk * 4) * 32 + dim;
  h1acc[base] += a0;
  h1acc[base + 32] += a1;
  h1acc[base + 64] += a2;
  h1acc[base + 96] += a3;
}

// ---------------- MLP ----------------

__global__ void mlp_k(const float* __restrict__ h1acc, const float* __restrict__ action,
                      const float* __restrict__ l1wlast, const float* __restrict__ l1b,
                      const float* __restrict__ l2w, const float* __restrict__ l2b,
                      float* __restrict__ h2) {
  __shared__ float w2s[1024];
  __shared__ float h1s[8][33];
  int tid = threadIdx.x;
  #pragma unroll
  for (int i = tid; i < 1024; i += 256) w2s[i] = l2w[i];
  int dim = tid & 31, nl = tid >> 5;
  int n = blockIdx.x * 8 + nl;
  float h1 = h1acc[n * 32 + dim] + action[n] * l1wlast[dim] + l1b[dim];
  h1s[nl][dim] = fmaxf(h1, 0.f);
  __syncthreads();
  float acc = l2b[dim];
  #pragma unroll
  for (int k = 0; k < 32; ++k) acc += h1s[nl][k] * w2s[k * 32 + dim];
  h2[n * 32 + dim] = fmaxf(acc, 0.f);
}

// ---------------- readout ----------------

__global__ void final_k(const float* __restrict__ h2, const float* __restrict__ l3w,
                        const float* __restrict__ l3b, float* __restrict__ out) {
  int gt = blockIdx.x * blockDim.x + threadIdx.x;
  int g = gt >> 6, lane = threadIdx.x & 63;
  float s = 0.f;
  #pragma unroll
  for (int p0 = 0; p0 < 192; p0 += 64) {
    int p = p0 + lane;
    s += h2[g * 192 + p] * l3w[p & 31];
  }
  #pragma unroll
  for (int off = 32; off; off >>= 1) s += __shfl_down(s, off, 64);
  if (lane == 0) out[g] = s + l3b[0];
}

// ---------------- host ----------------

extern "C" void kernel_launch(void* const* d_in, const int* in_sizes, int n_in,
                              void* d_out, int out_size, void* d_ws, size_t ws_size,
                              hipStream_t stream) {
  const float* state  = (const float*)d_in[0];
  const int*   ei     = (const int*)d_in[1];
  const float* action = (const float*)d_in[2];
  const float* W1 = (const float*)d_in[3];
  const float* b1 = (const float*)d_in[4];
  const float* W2 = (const float*)d_in[5];
  const float* b2 = (const float*)d_in[6];
  const float* W3 = (const float*)d_in[7];
  const float* b3 = (const float*)d_in[8];
  const float* l1w = (const float*)d_in[13];
  const float* l1b = (const float*)d_in[14];
  const float* l2w = (const float*)d_in[15];
  const float* l2b = (const float*)d_in[16];
  const float* l3w = (const float*)d_in[17];
  const float* l3b = (const float*)d_in[18];
  float* out = (float*)d_out;

  char* base = (char*)d_ws;
  size_t off = 0;
  auto carve = [&](size_t bytes) {
    char* q = base + off;
    off += (bytes + 255) & ~(size_t)255;
    return q;
  };
  __half* ysh    = (__half*)carve((size_t)NNODES * 256 * 2);
  __half* obufh  = (__half*)carve((size_t)NNODES * 256 * 2);
  __half* stateh = (__half*)carve((size_t)NNODES * 256 * 2);
  __half* whT1   = (__half*)carve(256 * 256 * 2);
  __half* whT2   = (__half*)carve(256 * 256 * 2);
  __half* whT3   = (__half*)carve(256 * 256 * 2);
  float* h1acc = (float*)carve((size_t)NNODES * 32 * 4);
  float* h2    = (float*)carve((size_t)NNODES * 32 * 4);
  float* dinv  = (float*)carve(NNODES * 4);
  int*   deg   = (int*)carve(NNODES * 4);
  int*   rs    = (int*)carve((NNODES + 1) * 4);
  int*   cursor= (int*)carve(NNODES * 4);
  unsigned short* csr = (unsigned short*)carve((size_t)NEDGES * 2);
  int*   bsum  = (int*)carve(256 * 4);

  hipMemsetAsync(deg, 0, NNODES * 4, stream);
  hipMemsetAsync(cursor, 0, NNODES * 4, stream);
  hipMemsetAsync(h1acc, 0, (size_t)NNODES * 32 * 4, stream);

  f2h_k<<<(NNODES * 256 / 8) / 256, 256, 0, stream>>>(state, stateh);
  wconv_k<<<256, 256, 0, stream>>>(W1, whT1);
  wconv_k<<<256, 256, 0, stream>>>(W2, whT2);
  wconv_k<<<256, 256, 0, stream>>>(W3, whT3);

  count_deg_k<<<NEDGES / 256, 256, 0, stream>>>(ei, deg);
  dinv_k<<<(NNODES + 255) / 256, 256, 0, stream>>>(deg, dinv);
  int nb = (NNODES + 255) / 256;
  scan1_k<<<nb, 256, 0, stream>>>(deg, rs, bsum);
  scan2_k<<<1, 256, 0, stream>>>(bsum, nb);
  scan3_k<<<nb, 256, 0, stream>>>(rs, bsum);
  scatter_k<<<NEDGES / 256, 256, 0, stream>>>(ei, rs, cursor, csr);

  const __half* whTs[5] = {whT1, whT2, whT3, whT3, whT3};
  const float*  bs[5]   = {b1, b2, b3, b3, b3};
  const __half* in = stateh;
  int mblocks = (NNODES + 127) / 128;   // 469
  int gchunks = (NNODES + 63) / 64;     // 938
  for (int layer = 0; layer < 5; ++layer) {
    gemm_mfma_k<<<mblocks * 2, 256, 0, stream>>>(in, whTs[layer], dinv, ysh);
    gather_k<<<gchunks * 8, 256, 0, stream>>>(ysh, rs, csr, dinv, bs[layer], obufh);
    skern_k<<<NNODES / 32, 256, 0, stream>>>(obufh, l1w + layer * 256 * 32, h1acc);
    in = obufh;
  }
  skern_k<<<NNODES / 32, 256, 0, stream>>>(stateh, l1w + 1280 * 32, h1acc);
  mlp_k<<<NNODES / 8, 256, 0, stream>>>(h1acc, action, l1w + 1536 * 32, l1b, l2w, l2b, h2);
  final_k<<<NGRAPH / 4, 256, 0, stream>>>(h2, l3w, l3b, out);
}

// Round 5
// 785.679 us; speedup vs baseline: 1.1885x; 1.1885x over previous
//
#include <hip/hip_runtime.h>
#include <hip/hip_fp16.h>

#define NNODES 60000
#define NEDGES 960000
#define NGRAPH 10000

struct __align__(16) H8 { __half2 h[4]; };
struct __align__(8)  H4 { __half2 h[2]; };

typedef _Float16 f16x8 __attribute__((ext_vector_type(8)));
typedef float f32x4 __attribute__((ext_vector_type(4)));

// ---------------- degree / CSR build ----------------

__global__ void count_deg_k(const int* __restrict__ ei, int* __restrict__ deg) {
  int e = blockIdx.x * blockDim.x + threadIdx.x;
  atomicAdd(&deg[ei[NEDGES + e]], 1);
}

__global__ void dinv_k(const int* __restrict__ deg, float* __restrict__ dinv) {
  int i = blockIdx.x * blockDim.x + threadIdx.x;
  if (i < NNODES) dinv[i] = rsqrtf((float)deg[i] + 1.0f);
}

__global__ void scan1_k(const int* __restrict__ deg, int* __restrict__ rs, int* __restrict__ bsum) {
  __shared__ int s[256];
  int tid = threadIdx.x;
  int i = blockIdx.x * 256 + tid;
  int v = (i < NNODES) ? deg[i] : 0;
  int x = v;
  s[tid] = x; __syncthreads();
  #pragma unroll
  for (int off = 1; off < 256; off <<= 1) {
    int t = (tid >= off) ? s[tid - off] : 0;
    __syncthreads();
    x += t; s[tid] = x; __syncthreads();
  }
  if (i < NNODES) rs[i] = x - v;
  if (tid == 255) bsum[blockIdx.x] = x;
}

__global__ void scan2_k(int* __restrict__ bsum, int nb) {
  __shared__ int s[256];
  int tid = threadIdx.x;
  int v = (tid < nb) ? bsum[tid] : 0;
  int x = v; s[tid] = x; __syncthreads();
  #pragma unroll
  for (int off = 1; off < 256; off <<= 1) {
    int t = (tid >= off) ? s[tid - off] : 0;
    __syncthreads();
    x += t; s[tid] = x; __syncthreads();
  }
  if (tid < nb) bsum[tid] = x - v;
}

__global__ void scan3_k(int* __restrict__ rs, const int* __restrict__ bsum) {
  int i = blockIdx.x * 256 + threadIdx.x;
  if (i < NNODES) rs[i] += bsum[blockIdx.x];
  if (i == 0) rs[NNODES] = NEDGES;
}

__global__ void scatter_k(const int* __restrict__ ei, const int* __restrict__ rs,
                          int* __restrict__ cursor, unsigned short* __restrict__ csr) {
  int e = blockIdx.x * blockDim.x + threadIdx.x;
  int s = ei[e], d = ei[NEDGES + e];
  int pos = rs[d] + atomicAdd(&cursor[d], 1);
  csr[pos] = (unsigned short)s;
}

// ---------------- fp32 -> fp16 convert (state) ----------------

__global__ void f2h_k(const float* __restrict__ in, __half* __restrict__ out) {
  int i = blockIdx.x * blockDim.x + threadIdx.x;   // one H8 per thread
  float4 a = *reinterpret_cast<const float4*>(in + (size_t)i * 8);
  float4 b = *reinterpret_cast<const float4*>(in + (size_t)i * 8 + 4);
  H8 o;
  o.h[0].x = __float2half_rn(a.x); o.h[0].y = __float2half_rn(a.y);
  o.h[1].x = __float2half_rn(a.z); o.h[1].y = __float2half_rn(a.w);
  o.h[2].x = __float2half_rn(b.x); o.h[2].y = __float2half_rn(b.y);
  o.h[3].x = __float2half_rn(b.z); o.h[3].y = __float2half_rn(b.w);
  *reinterpret_cast<H8*>(out + (size_t)i * 8) = o;
}

// ---------------- weight transpose+convert (all 3 weights in one launch) ----------------

__global__ void wconv3_k(const float* __restrict__ W1, const float* __restrict__ W2,
                         const float* __restrict__ W3, __half* __restrict__ T1,
                         __half* __restrict__ T2, __half* __restrict__ T3) {
  int n = blockIdx.x & 255, which = blockIdx.x >> 8, k = threadIdx.x;
  const float* W = which == 0 ? W1 : (which == 1 ? W2 : W3);
  __half* T = which == 0 ? T1 : (which == 1 ? T2 : T3);
  T[n * 256 + k] = __float2half_rn(W[k * 256 + n]);
}

// ---------------- MFMA GEMM: Y[r] = fp16((X @ W)[r] * dinv[r]) ----------------

#define LDP 56

__launch_bounds__(256)
__global__ void gemm_mfma_k(const __half* __restrict__ Xh, const __half* __restrict__ WhT,
                            const float* __restrict__ dinv, __half* __restrict__ Y) {
  __shared__ _Float16 As[128][LDP];
  __shared__ _Float16 Bs[128][LDP];
  const int tid = threadIdx.x;
  const int n0 = (blockIdx.x & 1) * 128;
  const int m0 = (blockIdx.x >> 1) * 128;
  const int lane = tid & 63;
  const int wid = tid >> 6;
  const int wr = wid >> 1, wc = wid & 1;
  const int li = lane & 15, lg = lane >> 4;

  f32x4 acc[4][4];
  #pragma unroll
  for (int i = 0; i < 4; ++i)
    #pragma unroll
    for (int j = 0; j < 4; ++j) acc[i][j] = (f32x4){0.f, 0.f, 0.f, 0.f};

  for (int k0 = 0; k0 < 256; k0 += 32) {
    #pragma unroll
    for (int l = 0; l < 2; ++l) {
      int f = tid + l * 256;
      int row = f >> 2, cq = (f & 3) * 8;
      int gr = m0 + row; if (gr >= NNODES) gr = NNODES - 1;
      *reinterpret_cast<H8*>(&As[row][cq]) =
          *reinterpret_cast<const H8*>(Xh + (size_t)gr * 256 + k0 + cq);
      *reinterpret_cast<H8*>(&Bs[row][cq]) =
          *reinterpret_cast<const H8*>(WhT + (size_t)(n0 + row) * 256 + k0 + cq);
    }
    __syncthreads();
    f16x8 a[4], b[4];
    #pragma unroll
    for (int rf = 0; rf < 4; ++rf)
      a[rf] = *reinterpret_cast<const f16x8*>(&As[wr * 64 + rf * 16 + li][lg * 8]);
    #pragma unroll
    for (int cf = 0; cf < 4; ++cf)
      b[cf] = *reinterpret_cast<const f16x8*>(&Bs[wc * 64 + cf * 16 + li][lg * 8]);
    #pragma unroll
    for (int rf = 0; rf < 4; ++rf)
      #pragma unroll
      for (int cf = 0; cf < 4; ++cf)
        acc[rf][cf] = __builtin_amdgcn_mfma_f32_16x16x32_f16(b[cf], a[rf], acc[rf][cf], 0, 0, 0);
    __syncthreads();
  }

  #pragma unroll
  for (int rf = 0; rf < 4; ++rf) {
    int r = m0 + wr * 64 + rf * 16 + li;
    if (r < NNODES) {
      float dv = dinv[r];
      #pragma unroll
      for (int cf = 0; cf < 4; ++cf) {
        int n = n0 + wc * 64 + cf * 16 + lg * 4;
        H4 o;
        o.h[0].x = __float2half_rn(acc[rf][cf][0] * dv);
        o.h[0].y = __float2half_rn(acc[rf][cf][1] * dv);
        o.h[1].x = __float2half_rn(acc[rf][cf][2] * dv);
        o.h[1].y = __float2half_rn(acc[rf][cf][3] * dv);
        *reinterpret_cast<H4*>(Y + (size_t)r * 256 + n) = o;
      }
    }
  }
}

// ---------------- gather: o[d] = fp16(relu(dinv[d]*(ys[d] + sum ys[src]) + b)) ----------
// half-wave (32 lanes) per node, full 512B row; 4-edge unroll for MLP.

__device__ inline void addH8(float* acc, const H8& v) {
  #pragma unroll
  for (int q = 0; q < 4; ++q) {
    acc[q * 2 + 0] += __low2float(v.h[q]);
    acc[q * 2 + 1] += __high2float(v.h[q]);
  }
}

__global__ void gather_k(const __half* __restrict__ ysh, const int* __restrict__ rs,
                         const unsigned short* __restrict__ csr, const float* __restrict__ dinv,
                         const float* __restrict__ bias, __half* __restrict__ out) {
  int tid = threadIdx.x;
  int lane = tid & 63;
  int wave = (blockIdx.x * blockDim.x + tid) >> 6;
  int d = wave * 2 + (lane >> 5);
  int c8 = (lane & 31) * 8;

  float acc[8];
  H8 self = *reinterpret_cast<const H8*>(ysh + (size_t)d * 256 + c8);
  #pragma unroll
  for (int q = 0; q < 4; ++q) {
    acc[q * 2 + 0] = __low2float(self.h[q]);
    acc[q * 2 + 1] = __high2float(self.h[q]);
  }

  int e = rs[d], end = rs[d + 1];
  for (; e + 3 < end; e += 4) {
    int s0 = csr[e], s1 = csr[e + 1], s2 = csr[e + 2], s3 = csr[e + 3];
    H8 v0 = *reinterpret_cast<const H8*>(ysh + (size_t)s0 * 256 + c8);
    H8 v1 = *reinterpret_cast<const H8*>(ysh + (size_t)s1 * 256 + c8);
    H8 v2 = *reinterpret_cast<const H8*>(ysh + (size_t)s2 * 256 + c8);
    H8 v3 = *reinterpret_cast<const H8*>(ysh + (size_t)s3 * 256 + c8);
    addH8(acc, v0);
    addH8(acc, v1);
    addH8(acc, v2);
    addH8(acc, v3);
  }
  for (; e < end; ++e) {
    int s0 = csr[e];
    H8 v0 = *reinterpret_cast<const H8*>(ysh + (size_t)s0 * 256 + c8);
    addH8(acc, v0);
  }

  float dv = dinv[d];
  float4 b0 = *reinterpret_cast<const float4*>(bias + c8);
  float4 b1 = *reinterpret_cast<const float4*>(bias + c8 + 4);
  float r0 = fmaxf(acc[0] * dv + b0.x, 0.f);
  float r1 = fmaxf(acc[1] * dv + b0.y, 0.f);
  float r2 = fmaxf(acc[2] * dv + b0.z, 0.f);
  float r3 = fmaxf(acc[3] * dv + b0.w, 0.f);
  float r4 = fmaxf(acc[4] * dv + b1.x, 0.f);
  float r5 = fmaxf(acc[5] * dv + b1.y, 0.f);
  float r6 = fmaxf(acc[6] * dv + b1.z, 0.f);
  float r7 = fmaxf(acc[7] * dv + b1.w, 0.f);
  H8 o;
  o.h[0].x = __float2half_rn(r0); o.h[0].y = __float2half_rn(r1);
  o.h[1].x = __float2half_rn(r2); o.h[1].y = __float2half_rn(r3);
  o.h[2].x = __float2half_rn(r4); o.h[2].y = __float2half_rn(r5);
  o.h[3].x = __float2half_rn(r6); o.h[3].y = __float2half_rn(r7);
  *reinterpret_cast<H8*>(out + (size_t)d * 256 + c8) = o;
}

// ---------------- skern: h1acc[32 rows/block] += in @ lw  (in fp16) ----------------

__launch_bounds__(256)
__global__ void skern_k(const __half* __restrict__ in, const float* __restrict__ lw,
                        float* __restrict__ h1acc) {
  __shared__ float os[32][256];
  int tid = threadIdx.x;
  int n0 = blockIdx.x * 32;
  #pragma unroll
  for (int l = 0; l < 4; ++l) {
    int f = tid + l * 256;
    int row = f >> 5, c8 = (f & 31) * 8;
    H8 v = *reinterpret_cast<const H8*>(in + (size_t)(n0 + row) * 256 + c8);
    float* dst = &os[row][c8];
    dst[0] = __low2float(v.h[0]); dst[1] = __high2float(v.h[0]);
    dst[2] = __low2float(v.h[1]); dst[3] = __high2float(v.h[1]);
    dst[4] = __low2float(v.h[2]); dst[5] = __high2float(v.h[2]);
    dst[6] = __low2float(v.h[3]); dst[7] = __high2float(v.h[3]);
  }
  __syncthreads();
  int dim = tid & 31, rblk = tid >> 5;
  float a0 = 0.f, a1 = 0.f, a2 = 0.f, a3 = 0.f;
  #pragma unroll 8
  for (int k = 0; k < 256; ++k) {
    float w = lw[k * 32 + dim];
    a0 += os[rblk * 4 + 0][k] * w;
    a1 += os[rblk * 4 + 1][k] * w;
    a2 += os[rblk * 4 + 2][k] * w;
    a3 += os[rblk * 4 + 3][k] * w;
  }
  int base = (n0 + rblk * 4) * 32 + dim;
  h1acc[base] += a0;
  h1acc[base + 32] += a1;
  h1acc[base + 64] += a2;
  h1acc[base + 96] += a3;
}

// ---------------- MLP ----------------

__global__ void mlp_k(const float* __restrict__ h1acc, const float* __restrict__ action,
                      const float* __restrict__ l1wlast, const float* __restrict__ l1b,
                      const float* __restrict__ l2w, const float* __restrict__ l2b,
                      float* __restrict__ h2) {
  __shared__ float w2s[1024];
  __shared__ float h1s[8][33];
  int tid = threadIdx.x;
  #pragma unroll
  for (int i = tid; i < 1024; i += 256) w2s[i] = l2w[i];
  int dim = tid & 31, nl = tid >> 5;
  int n = blockIdx.x * 8 + nl;
  float h1 = h1acc[n * 32 + dim] + action[n] * l1wlast[dim] + l1b[dim];
  h1s[nl][dim] = fmaxf(h1, 0.f);
  __syncthreads();
  float acc = l2b[dim];
  #pragma unroll
  for (int k = 0; k < 32; ++k) acc += h1s[nl][k] * w2s[k * 32 + dim];
  h2[n * 32 + dim] = fmaxf(acc, 0.f);
}

// ---------------- readout ----------------

__global__ void final_k(const float* __restrict__ h2, const float* __restrict__ l3w,
                        const float* __restrict__ l3b, float* __restrict__ out) {
  int gt = blockIdx.x * blockDim.x + threadIdx.x;
  int g = gt >> 6, lane = threadIdx.x & 63;
  float s = 0.f;
  #pragma unroll
  for (int p0 = 0; p0 < 192; p0 += 64) {
    int p = p0 + lane;
    s += h2[g * 192 + p] * l3w[p & 31];
  }
  #pragma unroll
  for (int off = 32; off; off >>= 1) s += __shfl_down(s, off, 64);
  if (lane == 0) out[g] = s + l3b[0];
}

// ---------------- host ----------------

extern "C" void kernel_launch(void* const* d_in, const int* in_sizes, int n_in,
                              void* d_out, int out_size, void* d_ws, size_t ws_size,
                              hipStream_t stream) {
  const float* state  = (const float*)d_in[0];
  const int*   ei     = (const int*)d_in[1];
  const float* action = (const float*)d_in[2];
  const float* W1 = (const float*)d_in[3];
  const float* b1 = (const float*)d_in[4];
  const float* W2 = (const float*)d_in[5];
  const float* b2 = (const float*)d_in[6];
  const float* W3 = (const float*)d_in[7];
  const float* b3 = (const float*)d_in[8];
  const float* l1w = (const float*)d_in[13];
  const float* l1b = (const float*)d_in[14];
  const float* l2w = (const float*)d_in[15];
  const float* l2b = (const float*)d_in[16];
  const float* l3w = (const float*)d_in[17];
  const float* l3b = (const float*)d_in[18];
  float* out = (float*)d_out;

  char* base = (char*)d_ws;
  size_t off = 0;
  auto carve = [&](size_t bytes) {
    char* q = base + off;
    off += (bytes + 255) & ~(size_t)255;
    return q;
  };
  __half* ysh    = (__half*)carve((size_t)NNODES * 256 * 2);
  __half* obufh  = (__half*)carve((size_t)NNODES * 256 * 2);
  __half* stateh = (__half*)carve((size_t)NNODES * 256 * 2);
  __half* whT1   = (__half*)carve(256 * 256 * 2);
  __half* whT2   = (__half*)carve(256 * 256 * 2);
  __half* whT3   = (__half*)carve(256 * 256 * 2);
  // deg | cursor | h1acc carved contiguously -> single memset
  char*  zbase = (char*)carve(0);
  int*   deg   = (int*)carve(NNODES * 4);
  int*   cursor= (int*)carve(NNODES * 4);
  float* h1acc = (float*)carve((size_t)NNODES * 32 * 4);
  size_t zlen  = (size_t)((char*)carve(0) - zbase);
  float* h2    = (float*)carve((size_t)NNODES * 32 * 4);
  float* dinv  = (float*)carve(NNODES * 4);
  int*   rs    = (int*)carve((NNODES + 1) * 4);
  unsigned short* csr = (unsigned short*)carve((size_t)NEDGES * 2);
  int*   bsum  = (int*)carve(256 * 4);

  hipMemsetAsync(zbase, 0, zlen, stream);

  f2h_k<<<(NNODES * 256 / 8) / 256, 256, 0, stream>>>(state, stateh);
  wconv3_k<<<256 * 3, 256, 0, stream>>>(W1, W2, W3, whT1, whT2, whT3);

  count_deg_k<<<NEDGES / 256, 256, 0, stream>>>(ei, deg);
  dinv_k<<<(NNODES + 255) / 256, 256, 0, stream>>>(deg, dinv);
  int nb = (NNODES + 255) / 256;
  scan1_k<<<nb, 256, 0, stream>>>(deg, rs, bsum);
  scan2_k<<<1, 256, 0, stream>>>(bsum, nb);
  scan3_k<<<nb, 256, 0, stream>>>(rs, bsum);
  scatter_k<<<NEDGES / 256, 256, 0, stream>>>(ei, rs, cursor, csr);

  const __half* whTs[5] = {whT1, whT2, whT3, whT3, whT3};
  const float*  bs[5]   = {b1, b2, b3, b3, b3};
  const __half* in = stateh;
  int mblocks = (NNODES + 127) / 128;   // 469
  for (int layer = 0; layer < 5; ++layer) {
    gemm_mfma_k<<<mblocks * 2, 256, 0, stream>>>(in, whTs[layer], dinv, ysh);
    gather_k<<<NNODES / 8, 256, 0, stream>>>(ysh, rs, csr, dinv, bs[layer], obufh);
    skern_k<<<NNODES / 32, 256, 0, stream>>>(obufh, l1w + layer * 256 * 32, h1acc);
    in = obufh;
  }
  skern_k<<<NNODES / 32, 256, 0, stream>>>(stateh, l1w + 1280 * 32, h1acc);
  mlp_k<<<NNODES / 8, 256, 0, stream>>>(h1acc, action, l1w + 1536 * 32, l1b, l2w, l2b, h2);
  final_k<<<NGRAPH / 4, 256, 0, stream>>>(h2, l3w, l3b, out);
}